// Round 13
// baseline (43.074 us; speedup 1.0000x reference)
//
#include <hip/hip_runtime.h>

#define T 4096
#define D 66
#define NL 3
#define NC 64          // scan chunks per modality
#define JC 64          // rows per chunk
#define DD (D * D)     // 4356
#define HSB 104        // H/Wt LDS stride in bf16 elems (16B multiple)
#define KTS 68         // KT LDS stride (fp32)

typedef short bf16x8 __attribute__((ext_vector_type(8)));
typedef float f32x4  __attribute__((ext_vector_type(4)));

__device__ __forceinline__ short f2bf(float f) {   // RNE f32 -> bf16
    unsigned int u = __builtin_bit_cast(unsigned int, f);
    u += 0x7fff + ((u >> 16) & 1);
    return (short)(u >> 16);
}

// write-through store: lands at the cross-XCD coherence point (no dirty L2)
__device__ __forceinline__ void st_sc(float* p, float v) {
    asm volatile("global_store_dword %0, %1, off sc0 sc1" :: "v"(p), "v"(v));
}

// ---------------------------------------------------------------------------
// Kernel 1: fused MFMA-MLP + in-chunk scan + (last block per modality) the
// chunk-offset scan. 320 blocks x 256 threads (4 waves).
//   Blocks 0..255 = (m, ch): 64-row MLP of modality m (K stays in LDS), scan
//   of those rows -> S (chunk-relative) / chunkSum (sc stores) / TM. The
//   64th-arriving block of each modality (relaxed atomicAdd on done[m]; no
//   spin => no deadlock) then shuffle-scans the 64 chunk sums per column into
//   chunkOff. chunkSum never transits a non-coherent L2: sc stores down,
//   sc gathers up (R10-validated protocol: st_sc -> vmcnt(0) -> relaxed add).
//   Blocks 256..319 = Q tiles (MLP only, writes Q row-major fp32).
// MLP per layer (MFMA): H [64][HSB] bf16 (K-pad 96), W^T [80][HSB] bf16
// (N-pad rows zero); wave wv owns row-tile wv; 3 A-frags + 5x3 B-frags ->
// 15 mfma_f32_16x16x32_bf16. C/D layout (m89): col=lane&15, row=(lane>>4)*4+reg.
// ---------------------------------------------------------------------------
__global__ __launch_bounds__(256) void mlp_scan_kernel(
    const float* __restrict__ x1, const float* __restrict__ x2,
    const float* __restrict__ x3, const float* __restrict__ x4,
    const float* __restrict__ wq, const float* __restrict__ bq,
    const float* __restrict__ wk, const float* __restrict__ bk,
    float* __restrict__ Q, float* __restrict__ S,
    float* __restrict__ chunkSum, float* __restrict__ chunkOff,
    float* __restrict__ TM, int* __restrict__ done)
{
    __shared__ short Hs[64 * HSB];
    __shared__ short Wt[80 * HSB];
    __shared__ float KT[D * KTS];
    __shared__ float side[3][64];          // [0],[1] = V cols; [2] = ts
    __shared__ int lastFlag;

    const int t    = threadIdx.x;
    const bool isQ = blockIdx.x >= 256;
    const int m    = isQ ? 0 : (blockIdx.x >> 6);
    const int j0   = (isQ ? (blockIdx.x - 256) : (blockIdx.x & 63)) * 64;
    const float* X  = (isQ || m == 0) ? x1 : (m == 1 ? x2 : (m == 2 ? x3 : x4));
    const float* W  = isQ ? wq : wk;
    const float* Bs = isQ ? bq : bk;

    // ---- stage x tile -> Hs (bf16) + side V/ts, float2-vectorized ----
    const float2* xt2 = (const float2*)(X + (size_t)j0 * D);   // 264B rows, 8B aligned
    for (int k = t; k < 64 * 33; k += 256) {
        const int r  = k / 33;
        const int dp = (k - r * 33) * 2;       // 0,2,...,64
        const float2 v = xt2[k];
        Hs[r * HSB + dp]     = f2bf(v.x);
        Hs[r * HSB + dp + 1] = f2bf(v.y);
        if (dp == 0)  { side[0][r] = v.x; side[1][r] = v.y; }
        if (dp == 64) { side[2][r] = v.y; }    // d = 65 = timestamp
    }
    // zero Hs K-pad cols 66..103
    for (int k = t; k < 64 * (HSB - D); k += 256) {
        const int r = k / (HSB - D);
        const int d = D + (k - r * (HSB - D));
        Hs[r * HSB + d] = 0;
    }
    // zero Wt fully (pads persist; stages only overwrite [col<66][k<66])
    {
        int* wz = (int*)Wt;
        for (int k = t; k < 80 * HSB / 2; k += 256) wz[k] = 0;
    }

    // prefetch layer-0 weights (in flight with staging)
    float wreg[18];
#pragma unroll
    for (int i = 0; i < 18; ++i) {
        const int k = t + i * 256;
        if (k < DD) wreg[i] = W[k];
    }

    const int lane = t & 63;
    const int wv   = t >> 6;
    const int lrow = lane & 15;            // A row / B col within tile
    const int kg   = (lane >> 4) * 8;      // k-group base
    const int cr0  = (lane >> 4) * 4;      // D row base within tile

    __syncthreads();

#pragma unroll 1
    for (int l = 0; l < NL; ++l) {
        // stage W^T (bf16) for this layer
#pragma unroll
        for (int i = 0; i < 18; ++i) {
            const int k = t + i * 256;
            if (k < DD) {
                const int kk = k / D;          // input dim (K)
                const int o  = k - kk * D;     // output col (N)
                Wt[o * HSB + kk] = f2bf(wreg[i]);
            }
        }
        __syncthreads();

        // prefetch next layer's weights (hides under mfma phase)
        if (l < NL - 1) {
            const float* Wg = W + (l + 1) * DD;
#pragma unroll
            for (int i = 0; i < 18; ++i) {
                const int k = t + i * 256;
                if (k < DD) wreg[i] = Wg[k];
            }
        }

        // A fragments (row tile = wv), k-steps 0/32/64
        const int abase = (wv * 16 + lrow) * HSB + kg;
        const bf16x8 a0 = *(const bf16x8*)&Hs[abase];
        const bf16x8 a1 = *(const bf16x8*)&Hs[abase + 32];
        const bf16x8 a2 = *(const bf16x8*)&Hs[abase + 64];

        f32x4 acc[5];
#pragma unroll
        for (int nt = 0; nt < 5; ++nt) {
            const short* wb = &Wt[(nt * 16 + lrow) * HSB + kg];
            f32x4 c = {0.0f, 0.0f, 0.0f, 0.0f};
            c = __builtin_amdgcn_mfma_f32_16x16x32_bf16(a0, *(const bf16x8*)(wb),      c, 0, 0, 0);
            c = __builtin_amdgcn_mfma_f32_16x16x32_bf16(a1, *(const bf16x8*)(wb + 32), c, 0, 0, 0);
            c = __builtin_amdgcn_mfma_f32_16x16x32_bf16(a2, *(const bf16x8*)(wb + 64), c, 0, 0, 0);
            acc[nt] = c;
        }
        __syncthreads();   // all Hs/Wt reads of this layer complete

        // epilogue: bias (+relu+cvt -> Hs) or final store
#pragma unroll
        for (int nt = 0; nt < 5; ++nt) {
            const int col = nt * 16 + lrow;
            const float bias = (col < D) ? Bs[l * D + col] : 0.0f;
#pragma unroll
            for (int r = 0; r < 4; ++r) {
                const int row = wv * 16 + cr0 + r;
                float v = acc[nt][r] + bias;
                if (l < NL - 1) {
                    v = fmaxf(v, 0.0f);
                    Hs[row * HSB + col] = f2bf(v);   // pad cols write 0
                } else if (isQ) {
                    if (col < D) Q[(size_t)(j0 + row) * D + col] = v;
                } else {
                    if (col < D) KT[col * KTS + row] = v;
                }
            }
        }
    }

    if (isQ) return;

    __syncthreads();

    // ===== scan tail: KT in LDS, V/ts from side buffer =====
    {
        const int c = t;
        if (c >= 144 && c < 144 + JC) TM[m * T + j0 + (c - 144)] = side[2][c - 144];
        if (c < 132) {
            const int d = c >> 1;
            const int v = c & 1;
            float run = 0.0f;
#pragma unroll 8
            for (int jj = 0; jj < JC; ++jj) {
                run = fmaf(KT[d * KTS + jj], side[v][jj], run);
                S[((size_t)m * T + j0 + jj) * 132 + c] = run;
            }
            st_sc(chunkSum + ((size_t)m * NC + j0 / JC) * 132 + c, run);
        }
    }

    // ===== arrive; 64th block of this modality runs the chunk-offset scan =====
    asm volatile("s_waitcnt vmcnt(0)" ::: "memory");   // drain sc stores
    __syncthreads();
    if (t == 0) {
        const int old = __hip_atomic_fetch_add(&done[m], 1, __ATOMIC_RELAXED,
                                               __HIP_MEMORY_SCOPE_AGENT);
        lastFlag = (old == NC - 1);
    }
    __syncthreads();
    if (!lastFlag) return;

    // chunk-offset scan for modality m: wave wv handles columns wv+4*idx,
    // idx 0..32. 8 sc-gathers in flight per asm block (waitcnt inside, so no
    // compiler-hoisting hazard); 6-step shuffle scan; exclusive -> chunkOff.
    {
        const float* base = chunkSum + ((size_t)m * NC + lane) * 132;
#pragma unroll 1
        for (int g = 0; g < 32; g += 8) {
            const float *p0 = base + (wv + 4 * (g + 0)), *p1 = base + (wv + 4 * (g + 1));
            const float *p2 = base + (wv + 4 * (g + 2)), *p3 = base + (wv + 4 * (g + 3));
            const float *p4 = base + (wv + 4 * (g + 4)), *p5 = base + (wv + 4 * (g + 5));
            const float *p6 = base + (wv + 4 * (g + 6)), *p7 = base + (wv + 4 * (g + 7));
            float a0, a1, a2, a3, a4, a5, a6, a7;
            asm volatile(
                "global_load_dword %0, %8, off sc0 sc1\n\t"
                "global_load_dword %1, %9, off sc0 sc1\n\t"
                "global_load_dword %2, %10, off sc0 sc1\n\t"
                "global_load_dword %3, %11, off sc0 sc1\n\t"
                "global_load_dword %4, %12, off sc0 sc1\n\t"
                "global_load_dword %5, %13, off sc0 sc1\n\t"
                "global_load_dword %6, %14, off sc0 sc1\n\t"
                "global_load_dword %7, %15, off sc0 sc1\n\t"
                "s_waitcnt vmcnt(0)"
                : "=&v"(a0), "=&v"(a1), "=&v"(a2), "=&v"(a3),
                  "=&v"(a4), "=&v"(a5), "=&v"(a6), "=&v"(a7)
                : "v"(p0), "v"(p1), "v"(p2), "v"(p3),
                  "v"(p4), "v"(p5), "v"(p6), "v"(p7));
            float va[8] = {a0, a1, a2, a3, a4, a5, a6, a7};
#pragma unroll
            for (int i = 0; i < 8; ++i) {
                float inc = va[i];
#pragma unroll
                for (int off = 1; off < 64; off <<= 1) {
                    const float y = __shfl_up(inc, off);
                    if (lane >= off) inc += y;
                }
                chunkOff[((size_t)m * NC + lane) * 132 + (wv + 4 * (g + i))] = inc - va[i];
            }
        }
        // remainder column idx 32 (c = wv + 128)
        {
            float vv;
            const float* pr = base + (wv + 128);
            asm volatile("global_load_dword %0, %1, off sc0 sc1\n\t"
                         "s_waitcnt vmcnt(0)"
                         : "=&v"(vv) : "v"(pr));
            float inc = vv;
#pragma unroll
            for (int off = 1; off < 64; off <<= 1) {
                const float y = __shfl_up(inc, off);
                if (lane >= off) inc += y;
            }
            chunkOff[((size_t)m * NC + lane) * 132 + (wv + 128)] = inc - vv;
        }
    }
}

// ---------------------------------------------------------------------------
// Kernel 2: gather + dot, one wave per output row (unchanged R11/R12).
// ---------------------------------------------------------------------------
__global__ __launch_bounds__(256) void out_kernel(
    const float* __restrict__ Q, const float* __restrict__ S,
    const float* __restrict__ chunkOff, const float* __restrict__ TM,
    float* __restrict__ out)
{
    __shared__ float segEnd[4][64];
    const int w    = threadIdx.x >> 6;
    const int lane = threadIdx.x & 63;
    const int i    = blockIdx.x * 4 + w;

    segEnd[w][lane] = TM[w * T + lane * 64 + 63];
    const float t1i = TM[i];
    const float q0  = Q[(size_t)i * D + lane];
    const float q1  = (lane < 2) ? Q[(size_t)i * D + 64 + lane] : 0.0f;
    float acc0 = 0.0f, acc1 = 0.0f;
    __syncthreads();

    int seg[4];
#pragma unroll
    for (int mm = 0; mm < 4; ++mm) {
        const unsigned long long b = __ballot(segEnd[mm][lane] <= t1i);
        const int hi = __popcll(b);
        seg[mm] = (hi < 63) ? hi : 63;
    }
    int idx[4];
#pragma unroll
    for (int mm = 0; mm < 4; ++mm) {
        const float sv = TM[mm * T + seg[mm] * 64 + lane];
        const unsigned long long b = __ballot(sv <= t1i);
        idx[mm] = seg[mm] * 64 + __popcll(b) - 1;
    }

#pragma unroll
    for (int mm = 0; mm < 4; ++mm) {
        if (idx[mm] >= 0) {
            const float* sp = S + ((size_t)mm * T + idx[mm]) * 132;
            const float* op = chunkOff + ((size_t)mm * NC + (idx[mm] / JC)) * 132;
            const float2 s0 = *(const float2*)(sp + lane * 2);
            const float2 c0 = *(const float2*)(op + lane * 2);
            acc0 = fmaf(q0, s0.x + c0.x, acc0);
            acc1 = fmaf(q0, s0.y + c0.y, acc1);
            if (lane < 2) {
                const float2 s1 = *(const float2*)(sp + 128 + lane * 2);
                const float2 c1 = *(const float2*)(op + 128 + lane * 2);
                acc0 = fmaf(q1, s1.x + c1.x, acc0);
                acc1 = fmaf(q1, s1.y + c1.y, acc1);
            }
        }
    }

#pragma unroll
    for (int off = 32; off >= 1; off >>= 1) {
        acc0 += __shfl_down(acc0, off);
        acc1 += __shfl_down(acc1, off);
    }
    if (lane == 0) {
        out[(size_t)i * 2 + 0] = acc0;
        out[(size_t)i * 2 + 1] = acc1;
    }
}

extern "C" void kernel_launch(void* const* d_in, const int* in_sizes, int n_in,
                              void* d_out, int out_size, void* d_ws, size_t ws_size,
                              hipStream_t stream)
{
    (void)in_sizes; (void)n_in; (void)out_size; (void)ws_size;
    const float* x1 = (const float*)d_in[0];
    const float* x2 = (const float*)d_in[1];
    const float* x3 = (const float*)d_in[2];
    const float* x4 = (const float*)d_in[3];
    const float* wq = (const float*)d_in[4];
    const float* bq = (const float*)d_in[5];
    const float* wk = (const float*)d_in[6];
    const float* bk = (const float*)d_in[7];

    float* ws = (float*)d_ws;
    float* Q        = ws;                  // 4096*66            = 270336
    float* S        = ws + 270336;         // 4*4096*132         = 2162688
    float* chunkSum = ws + 2433024;        // 4*NC*132           = 33792
    float* chunkOff = ws + 2466816;        // 4*NC*132           = 33792
    float* TM       = ws + 2500608;        // 4*4096             = 16384
    int*   done     = (int*)(ws + 2516992);// 4 ints

    hipMemsetAsync(done, 0, 4 * sizeof(int), stream);

    mlp_scan_kernel<<<320, 256, 0, stream>>>(x1, x2, x3, x4, wq, bq, wk, bk,
                                             Q, S, chunkSum, chunkOff, TM, done);
    out_kernel<<<1024, 256, 0, stream>>>(Q, S, chunkOff, TM, (float*)d_out);
}

// Round 14
// 35.733 us; speedup vs baseline: 1.2054x; 1.2054x over previous
//
#include <hip/hip_runtime.h>

#define T 4096
#define D 66
#define NL 3
#define NC 64          // scan chunks per modality
#define JC 64          // rows per chunk
#define DD (D * D)     // 4356
#define HSB 104        // H/Wt LDS stride in bf16 elems (16B multiple)
#define KTS 68         // KT LDS stride (fp32)

typedef short bf16x8 __attribute__((ext_vector_type(8)));
typedef float f32x4  __attribute__((ext_vector_type(4)));

__device__ __forceinline__ short f2bf(float f) {   // RNE f32 -> bf16
    unsigned int u = __builtin_bit_cast(unsigned int, f);
    u += 0x7fff + ((u >> 16) & 1);
    return (short)(u >> 16);
}

// ---------------------------------------------------------------------------
// Kernel 1: fused MFMA-MLP + in-chunk scan (R12 known-good, 29.5us config).
// Blocks 0..255 = (m, ch): 64-row MLP of modality m (K stays in LDS), then
// scan of those 64 rows -> S (chunk-relative) / chunkSum / TM.
// Blocks 256..319 = Q tiles (MLP only, Q row-major fp32 to global).
// MLP per layer (MFMA): H [64][HSB] bf16 (K-padded to 96 with zeros),
// W^T [80][HSB] bf16 (N-pad rows zero); wave wv owns row-tile wv;
// 3 A-frags + 5x3 B-frags (ds_read_b128) -> 15 mfma_f32_16x16x32_bf16.
// C/D layout (m89-verified): col = lane&15, row = (lane>>4)*4 + reg.
// ---------------------------------------------------------------------------
__global__ __launch_bounds__(256) void mlp_scan_kernel(
    const float* __restrict__ x1, const float* __restrict__ x2,
    const float* __restrict__ x3, const float* __restrict__ x4,
    const float* __restrict__ wq, const float* __restrict__ bq,
    const float* __restrict__ wk, const float* __restrict__ bk,
    float* __restrict__ Q, float* __restrict__ S,
    float* __restrict__ chunkSum, float* __restrict__ TM)
{
    __shared__ short Hs[64 * HSB];
    __shared__ short Wt[80 * HSB];
    __shared__ float KT[D * KTS];
    __shared__ float side[3][64];          // [0],[1] = V cols; [2] = ts

    const int t    = threadIdx.x;
    const bool isQ = blockIdx.x >= 256;
    const int m    = isQ ? 0 : (blockIdx.x >> 6);
    const int j0   = (isQ ? (blockIdx.x - 256) : (blockIdx.x & 63)) * 64;
    const float* X  = (isQ || m == 0) ? x1 : (m == 1 ? x2 : (m == 2 ? x3 : x4));
    const float* W  = isQ ? wq : wk;
    const float* Bs = isQ ? bq : bk;

    // ---- stage x tile -> Hs (bf16) + side V/ts, float2-vectorized ----
    const float2* xt2 = (const float2*)(X + (size_t)j0 * D);   // 264B rows, 8B aligned
    for (int k = t; k < 64 * 33; k += 256) {
        const int r  = k / 33;
        const int dp = (k - r * 33) * 2;       // 0,2,...,64
        const float2 v = xt2[k];
        Hs[r * HSB + dp]     = f2bf(v.x);
        Hs[r * HSB + dp + 1] = f2bf(v.y);
        if (dp == 0)  { side[0][r] = v.x; side[1][r] = v.y; }
        if (dp == 64) { side[2][r] = v.y; }    // d = 65 = timestamp
    }
    // zero Hs K-pad cols 66..103
    for (int k = t; k < 64 * (HSB - D); k += 256) {
        const int r = k / (HSB - D);
        const int d = D + (k - r * (HSB - D));
        Hs[r * HSB + d] = 0;
    }
    // zero Wt fully (pads persist; stages only overwrite [col<66][k<66])
    {
        int* wz = (int*)Wt;
        for (int k = t; k < 80 * HSB / 2; k += 256) wz[k] = 0;
    }

    // prefetch layer-0 weights (in flight with staging)
    float wreg[18];
#pragma unroll
    for (int i = 0; i < 18; ++i) {
        const int k = t + i * 256;
        if (k < DD) wreg[i] = W[k];
    }

    const int lane = t & 63;
    const int wv   = t >> 6;
    const int lrow = lane & 15;            // A row / B col within tile
    const int kg   = (lane >> 4) * 8;      // k-group base
    const int cr0  = (lane >> 4) * 4;      // D row base within tile

    __syncthreads();

#pragma unroll 1
    for (int l = 0; l < NL; ++l) {
        // stage W^T (bf16) for this layer
#pragma unroll
        for (int i = 0; i < 18; ++i) {
            const int k = t + i * 256;
            if (k < DD) {
                const int kk = k / D;          // input dim (K)
                const int o  = k - kk * D;     // output col (N)
                Wt[o * HSB + kk] = f2bf(wreg[i]);
            }
        }
        __syncthreads();

        // prefetch next layer's weights (hides under mfma phase)
        if (l < NL - 1) {
            const float* Wg = W + (l + 1) * DD;
#pragma unroll
            for (int i = 0; i < 18; ++i) {
                const int k = t + i * 256;
                if (k < DD) wreg[i] = Wg[k];
            }
        }

        // A fragments (row tile = wv), k-steps 0/32/64
        const int abase = (wv * 16 + lrow) * HSB + kg;
        const bf16x8 a0 = *(const bf16x8*)&Hs[abase];
        const bf16x8 a1 = *(const bf16x8*)&Hs[abase + 32];
        const bf16x8 a2 = *(const bf16x8*)&Hs[abase + 64];

        f32x4 acc[5];
#pragma unroll
        for (int nt = 0; nt < 5; ++nt) {
            const short* wb = &Wt[(nt * 16 + lrow) * HSB + kg];
            f32x4 c = {0.0f, 0.0f, 0.0f, 0.0f};
            c = __builtin_amdgcn_mfma_f32_16x16x32_bf16(a0, *(const bf16x8*)(wb),      c, 0, 0, 0);
            c = __builtin_amdgcn_mfma_f32_16x16x32_bf16(a1, *(const bf16x8*)(wb + 32), c, 0, 0, 0);
            c = __builtin_amdgcn_mfma_f32_16x16x32_bf16(a2, *(const bf16x8*)(wb + 64), c, 0, 0, 0);
            acc[nt] = c;
        }
        __syncthreads();   // all Hs/Wt reads of this layer complete

        // epilogue: bias (+relu+cvt -> Hs) or final store
#pragma unroll
        for (int nt = 0; nt < 5; ++nt) {
            const int col = nt * 16 + lrow;
            const float bias = (col < D) ? Bs[l * D + col] : 0.0f;
#pragma unroll
            for (int r = 0; r < 4; ++r) {
                const int row = wv * 16 + cr0 + r;
                float v = acc[nt][r] + bias;
                if (l < NL - 1) {
                    v = fmaxf(v, 0.0f);
                    Hs[row * HSB + col] = f2bf(v);   // pad cols write 0
                } else if (isQ) {
                    if (col < D) Q[(size_t)(j0 + row) * D + col] = v;
                } else {
                    if (col < D) KT[col * KTS + row] = v;
                }
            }
        }
    }

    __syncthreads();

    // ===== scan tail (K blocks): KT in LDS, V/ts from side buffer =====
    if (!isQ) {
        const int c = t;
        if (c >= 144 && c < 144 + JC) TM[m * T + j0 + (c - 144)] = side[2][c - 144];
        if (c < 132) {
            const int d = c >> 1;
            const int v = c & 1;
            float run = 0.0f;
#pragma unroll 8
            for (int jj = 0; jj < JC; ++jj) {
                run = fmaf(KT[d * KTS + jj], side[v][jj], run);
                S[((size_t)m * T + j0 + jj) * 132 + c] = run;
            }
            chunkSum[((size_t)m * NC + j0 / JC) * 132 + c] = run;
        }
    }
}

// ---------------------------------------------------------------------------
// Kernel 2: exclusive scan of chunk sums, wave-parallel (unchanged R12).
// ---------------------------------------------------------------------------
__global__ __launch_bounds__(256) void chunkscan_kernel(
    const float* __restrict__ chunkSum, float* __restrict__ chunkOff)
{
    const int wv   = threadIdx.x >> 6;
    const int lane = threadIdx.x & 63;     // chunk index (NC == 64)
    const int c    = blockIdx.x * 4 + wv;  // 0..131
    const int m    = blockIdx.y;
    if (c >= 132) return;

    const float v = chunkSum[((size_t)m * NC + lane) * 132 + c];
    float inc = v;
#pragma unroll
    for (int off = 1; off < 64; off <<= 1) {
        const float y = __shfl_up(inc, off);
        if (lane >= off) inc += y;
    }
    chunkOff[((size_t)m * NC + lane) * 132 + c] = inc - v;
}

// ---------------------------------------------------------------------------
// Kernel 3: gather + dot. 256 blocks x 4-row grid-stride (was 1024 blocks):
// shorter dispatch ramp; segEnd LDS table staged once per block and reused
// across 4 iterations; iterations' S gathers pipeline within each wave.
// ---------------------------------------------------------------------------
__global__ __launch_bounds__(256) void out_kernel(
    const float* __restrict__ Q, const float* __restrict__ S,
    const float* __restrict__ chunkOff, const float* __restrict__ TM,
    float* __restrict__ out)
{
    __shared__ float segEnd[4][64];
    const int w    = threadIdx.x >> 6;
    const int lane = threadIdx.x & 63;

    segEnd[w][lane] = TM[w * T + lane * 64 + 63];   // wave w stages modality w
    __syncthreads();

#pragma unroll 1
    for (int i = blockIdx.x * 4 + w; i < T; i += 1024) {
        const float t1i = TM[i];               // modality 0 times == t1
        const float q0  = Q[(size_t)i * D + lane];
        const float q1  = (lane < 2) ? Q[(size_t)i * D + 64 + lane] : 0.0f;
        float acc0 = 0.0f, acc1 = 0.0f;

        int seg[4];
#pragma unroll
        for (int mm = 0; mm < 4; ++mm) {
            const unsigned long long b = __ballot(segEnd[mm][lane] <= t1i);
            const int hi = __popcll(b);
            seg[mm] = (hi < 63) ? hi : 63;
        }
        int idx[4];
#pragma unroll
        for (int mm = 0; mm < 4; ++mm) {
            const float sv = TM[mm * T + seg[mm] * 64 + lane];
            const unsigned long long b = __ballot(sv <= t1i);
            idx[mm] = seg[mm] * 64 + __popcll(b) - 1;   // pos-1; -1 => none
        }

#pragma unroll
        for (int mm = 0; mm < 4; ++mm) {
            if (idx[mm] >= 0) {
                const float* sp = S + ((size_t)mm * T + idx[mm]) * 132;
                const float* op = chunkOff + ((size_t)mm * NC + (idx[mm] / JC)) * 132;
                const float2 s0 = *(const float2*)(sp + lane * 2);
                const float2 c0 = *(const float2*)(op + lane * 2);
                acc0 = fmaf(q0, s0.x + c0.x, acc0);
                acc1 = fmaf(q0, s0.y + c0.y, acc1);
                if (lane < 2) {
                    const float2 s1 = *(const float2*)(sp + 128 + lane * 2);
                    const float2 c1 = *(const float2*)(op + 128 + lane * 2);
                    acc0 = fmaf(q1, s1.x + c1.x, acc0);
                    acc1 = fmaf(q1, s1.y + c1.y, acc1);
                }
            }
        }

#pragma unroll
        for (int off = 32; off >= 1; off >>= 1) {
            acc0 += __shfl_down(acc0, off);
            acc1 += __shfl_down(acc1, off);
        }
        if (lane == 0) {
            out[(size_t)i * 2 + 0] = acc0;
            out[(size_t)i * 2 + 1] = acc1;
        }
    }
}

extern "C" void kernel_launch(void* const* d_in, const int* in_sizes, int n_in,
                              void* d_out, int out_size, void* d_ws, size_t ws_size,
                              hipStream_t stream)
{
    (void)in_sizes; (void)n_in; (void)out_size; (void)ws_size;
    const float* x1 = (const float*)d_in[0];
    const float* x2 = (const float*)d_in[1];
    const float* x3 = (const float*)d_in[2];
    const float* x4 = (const float*)d_in[3];
    const float* wq = (const float*)d_in[4];
    const float* bq = (const float*)d_in[5];
    const float* wk = (const float*)d_in[6];
    const float* bk = (const float*)d_in[7];

    float* ws = (float*)d_ws;
    float* Q        = ws;                  // 4096*66            = 270336
    float* S        = ws + 270336;         // 4*4096*132         = 2162688
    float* chunkSum = ws + 2433024;        // 4*NC*132           = 33792
    float* chunkOff = ws + 2466816;        // 4*NC*132           = 33792
    float* TM       = ws + 2500608;        // 4*4096             = 16384
                                           // total ~10.07 MB

    mlp_scan_kernel<<<320, 256, 0, stream>>>(x1, x2, x3, x4, wq, bq, wk, bk,
                                             Q, S, chunkSum, TM);
    chunkscan_kernel<<<dim3(33, 4), 256, 0, stream>>>(chunkSum, chunkOff);
    out_kernel<<<256, 256, 0, stream>>>(Q, S, chunkOff, TM, (float*)d_out);
}

// Round 15
// 27.822 us; speedup vs baseline: 1.5482x; 1.2844x over previous
//
#include <hip/hip_runtime.h>

#define T 4096
#define D 66
#define NL 3
#define NC 64          // scan chunks per modality
#define JC 64          // rows per chunk
#define DD (D * D)     // 4356
#define HSB 104        // H/Wt LDS stride in bf16 elems (16B multiple)
#define KTS 68         // KT LDS stride (fp32)

typedef short bf16x8 __attribute__((ext_vector_type(8)));
typedef float f32x4  __attribute__((ext_vector_type(4)));

__device__ __forceinline__ unsigned short f2bf(float f) {   // RNE f32 -> bf16
    unsigned int u = __builtin_bit_cast(unsigned int, f);
    u += 0x7fff + ((u >> 16) & 1);
    return (unsigned short)(u >> 16);
}
__device__ __forceinline__ float bf2f(unsigned short b) {
    return __builtin_bit_cast(float, (unsigned int)b << 16);
}

// ---------------------------------------------------------------------------
// Kernel 1: fused MFMA-MLP + in-chunk scan (R12 structure; S stored bf16).
// Blocks 0..255 = (m, ch): 64-row MLP of modality m (K stays in LDS), then
// scan of those 64 rows -> Sb (bf16 chunk-relative cumsum) / chunkSum (fp32)
// / TM. Blocks 256..319 = Q tiles (MLP only, Q row-major fp32 to global).
// MLP per layer (MFMA): H [64][HSB] bf16 (K-padded to 96 with zeros),
// W^T [80][HSB] bf16 (N-pad rows zero); wave wv owns row-tile wv;
// 3 A-frags + 5x3 B-frags (ds_read_b128) -> 15 mfma_f32_16x16x32_bf16.
// C/D layout (m89-verified): col = lane&15, row = (lane>>4)*4 + reg.
// ---------------------------------------------------------------------------
__global__ __launch_bounds__(256) void mlp_scan_kernel(
    const float* __restrict__ x1, const float* __restrict__ x2,
    const float* __restrict__ x3, const float* __restrict__ x4,
    const float* __restrict__ wq, const float* __restrict__ bq,
    const float* __restrict__ wk, const float* __restrict__ bk,
    float* __restrict__ Q, unsigned short* __restrict__ Sb,
    float* __restrict__ chunkSum, float* __restrict__ TM)
{
    __shared__ short Hs[64 * HSB];
    __shared__ short Wt[80 * HSB];
    __shared__ float KT[D * KTS];
    __shared__ float side[3][64];          // [0],[1] = V cols; [2] = ts

    const int t    = threadIdx.x;
    const bool isQ = blockIdx.x >= 256;
    const int m    = isQ ? 0 : (blockIdx.x >> 6);
    const int j0   = (isQ ? (blockIdx.x - 256) : (blockIdx.x & 63)) * 64;
    const float* X  = (isQ || m == 0) ? x1 : (m == 1 ? x2 : (m == 2 ? x3 : x4));
    const float* W  = isQ ? wq : wk;
    const float* Bs = isQ ? bq : bk;

    // ---- stage x tile -> Hs (bf16) + side V/ts, float2-vectorized ----
    const float2* xt2 = (const float2*)(X + (size_t)j0 * D);   // 264B rows, 8B aligned
    for (int k = t; k < 64 * 33; k += 256) {
        const int r  = k / 33;
        const int dp = (k - r * 33) * 2;       // 0,2,...,64
        const float2 v = xt2[k];
        Hs[r * HSB + dp]     = f2bf(v.x);
        Hs[r * HSB + dp + 1] = f2bf(v.y);
        if (dp == 0)  { side[0][r] = v.x; side[1][r] = v.y; }
        if (dp == 64) { side[2][r] = v.y; }    // d = 65 = timestamp
    }
    // zero Hs K-pad cols 66..103
    for (int k = t; k < 64 * (HSB - D); k += 256) {
        const int r = k / (HSB - D);
        const int d = D + (k - r * (HSB - D));
        Hs[r * HSB + d] = 0;
    }
    // zero Wt fully (pads persist; stages only overwrite [col<66][k<66])
    {
        int* wz = (int*)Wt;
        for (int k = t; k < 80 * HSB / 2; k += 256) wz[k] = 0;
    }

    // prefetch layer-0 weights (in flight with staging)
    float wreg[18];
#pragma unroll
    for (int i = 0; i < 18; ++i) {
        const int k = t + i * 256;
        if (k < DD) wreg[i] = W[k];
    }

    const int lane = t & 63;
    const int wv   = t >> 6;
    const int lrow = lane & 15;            // A row / B col within tile
    const int kg   = (lane >> 4) * 8;      // k-group base
    const int cr0  = (lane >> 4) * 4;      // D row base within tile

    __syncthreads();

#pragma unroll 1
    for (int l = 0; l < NL; ++l) {
        // stage W^T (bf16) for this layer
#pragma unroll
        for (int i = 0; i < 18; ++i) {
            const int k = t + i * 256;
            if (k < DD) {
                const int kk = k / D;          // input dim (K)
                const int o  = k - kk * D;     // output col (N)
                Wt[o * HSB + kk] = f2bf(wreg[i]);
            }
        }
        __syncthreads();

        // prefetch next layer's weights (hides under mfma phase)
        if (l < NL - 1) {
            const float* Wg = W + (l + 1) * DD;
#pragma unroll
            for (int i = 0; i < 18; ++i) {
                const int k = t + i * 256;
                if (k < DD) wreg[i] = Wg[k];
            }
        }

        // A fragments (row tile = wv), k-steps 0/32/64
        const int abase = (wv * 16 + lrow) * HSB + kg;
        const bf16x8 a0 = *(const bf16x8*)&Hs[abase];
        const bf16x8 a1 = *(const bf16x8*)&Hs[abase + 32];
        const bf16x8 a2 = *(const bf16x8*)&Hs[abase + 64];

        f32x4 acc[5];
#pragma unroll
        for (int nt = 0; nt < 5; ++nt) {
            const short* wb = &Wt[(nt * 16 + lrow) * HSB + kg];
            f32x4 c = {0.0f, 0.0f, 0.0f, 0.0f};
            c = __builtin_amdgcn_mfma_f32_16x16x32_bf16(a0, *(const bf16x8*)(wb),      c, 0, 0, 0);
            c = __builtin_amdgcn_mfma_f32_16x16x32_bf16(a1, *(const bf16x8*)(wb + 32), c, 0, 0, 0);
            c = __builtin_amdgcn_mfma_f32_16x16x32_bf16(a2, *(const bf16x8*)(wb + 64), c, 0, 0, 0);
            acc[nt] = c;
        }
        __syncthreads();   // all Hs/Wt reads of this layer complete

        // epilogue: bias (+relu+cvt -> Hs) or final store
#pragma unroll
        for (int nt = 0; nt < 5; ++nt) {
            const int col = nt * 16 + lrow;
            const float bias = (col < D) ? Bs[l * D + col] : 0.0f;
#pragma unroll
            for (int r = 0; r < 4; ++r) {
                const int row = wv * 16 + cr0 + r;
                float v = acc[nt][r] + bias;
                if (l < NL - 1) {
                    v = fmaxf(v, 0.0f);
                    Hs[row * HSB + col] = f2bf(v);   // pad cols write 0
                } else if (isQ) {
                    if (col < D) Q[(size_t)(j0 + row) * D + col] = v;
                } else {
                    if (col < D) KT[col * KTS + row] = v;
                }
            }
        }
    }

    __syncthreads();

    // ===== scan tail (K blocks): KT in LDS, V/ts from side buffer =====
    if (!isQ) {
        const int c = t;
        if (c >= 144 && c < 144 + JC) TM[m * T + j0 + (c - 144)] = side[2][c - 144];
        if (c < 132) {
            const int d = c >> 1;
            const int v = c & 1;
            float run = 0.0f;
#pragma unroll 8
            for (int jj = 0; jj < JC; ++jj) {
                run = fmaf(KT[d * KTS + jj], side[v][jj], run);
                Sb[((size_t)m * T + j0 + jj) * 132 + c] = f2bf(run);
            }
            chunkSum[((size_t)m * NC + j0 / JC) * 132 + c] = run;
        }
    }
}

// ---------------------------------------------------------------------------
// Kernel 2: exclusive scan of chunk sums, wave-parallel (unchanged R12).
// ---------------------------------------------------------------------------
__global__ __launch_bounds__(256) void chunkscan_kernel(
    const float* __restrict__ chunkSum, float* __restrict__ chunkOff)
{
    const int wv   = threadIdx.x >> 6;
    const int lane = threadIdx.x & 63;     // chunk index (NC == 64)
    const int c    = blockIdx.x * 4 + wv;  // 0..131
    const int m    = blockIdx.y;
    if (c >= 132) return;

    const float v = chunkSum[((size_t)m * NC + lane) * 132 + c];
    float inc = v;
#pragma unroll
    for (int off = 1; off < 64; off <<= 1) {
        const float y = __shfl_up(inc, off);
        if (lane >= off) inc += y;
    }
    chunkOff[((size_t)m * NC + lane) * 132 + c] = inc - v;
}

// ---------------------------------------------------------------------------
// Kernel 3: gather + dot. 1024 blocks, one wave per output row (R12 form --
// TLP does the latency hiding; R14's 256-block grid-stride regressed).
// S rows are bf16 (ushort2 loads), chunk offsets fp32.
// ---------------------------------------------------------------------------
__global__ __launch_bounds__(256) void out_kernel(
    const float* __restrict__ Q, const unsigned short* __restrict__ Sb,
    const float* __restrict__ chunkOff, const float* __restrict__ TM,
    float* __restrict__ out)
{
    __shared__ float segEnd[4][64];
    const int w    = threadIdx.x >> 6;
    const int lane = threadIdx.x & 63;
    const int i    = blockIdx.x * 4 + w;

    segEnd[w][lane] = TM[w * T + lane * 64 + 63];   // wave w stages modality w
    const float t1i = TM[i];               // modality 0 times == t1
    const float q0  = Q[(size_t)i * D + lane];
    const float q1  = (lane < 2) ? Q[(size_t)i * D + 64 + lane] : 0.0f;
    float acc0 = 0.0f, acc1 = 0.0f;
    __syncthreads();

    int seg[4];
#pragma unroll
    for (int mm = 0; mm < 4; ++mm) {
        const unsigned long long b = __ballot(segEnd[mm][lane] <= t1i);
        const int hi = __popcll(b);
        seg[mm] = (hi < 63) ? hi : 63;
    }
    int idx[4];
#pragma unroll
    for (int mm = 0; mm < 4; ++mm) {
        const float sv = TM[mm * T + seg[mm] * 64 + lane];
        const unsigned long long b = __ballot(sv <= t1i);
        idx[mm] = seg[mm] * 64 + __popcll(b) - 1;   // pos-1; -1 => none
    }

#pragma unroll
    for (int mm = 0; mm < 4; ++mm) {
        if (idx[mm] >= 0) {
            const unsigned short* sp = Sb + ((size_t)mm * T + idx[mm]) * 132;
            const float* op = chunkOff + ((size_t)mm * NC + (idx[mm] / JC)) * 132;
            const ushort2 s0 = *(const ushort2*)(sp + lane * 2);
            const float2  c0 = *(const float2*)(op + lane * 2);
            acc0 = fmaf(q0, bf2f(s0.x) + c0.x, acc0);
            acc1 = fmaf(q0, bf2f(s0.y) + c0.y, acc1);
            if (lane < 2) {
                const ushort2 s1 = *(const ushort2*)(sp + 128 + lane * 2);
                const float2  c1 = *(const float2*)(op + 128 + lane * 2);
                acc0 = fmaf(q1, bf2f(s1.x) + c1.x, acc0);
                acc1 = fmaf(q1, bf2f(s1.y) + c1.y, acc1);
            }
        }
    }

#pragma unroll
    for (int off = 32; off >= 1; off >>= 1) {
        acc0 += __shfl_down(acc0, off);
        acc1 += __shfl_down(acc1, off);
    }
    if (lane == 0) {
        out[(size_t)i * 2 + 0] = acc0;
        out[(size_t)i * 2 + 1] = acc1;
    }
}

extern "C" void kernel_launch(void* const* d_in, const int* in_sizes, int n_in,
                              void* d_out, int out_size, void* d_ws, size_t ws_size,
                              hipStream_t stream)
{
    (void)in_sizes; (void)n_in; (void)out_size; (void)ws_size;
    const float* x1 = (const float*)d_in[0];
    const float* x2 = (const float*)d_in[1];
    const float* x3 = (const float*)d_in[2];
    const float* x4 = (const float*)d_in[3];
    const float* wq = (const float*)d_in[4];
    const float* bq = (const float*)d_in[5];
    const float* wk = (const float*)d_in[6];
    const float* bk = (const float*)d_in[7];

    float* ws = (float*)d_ws;
    float*          Q        = ws;                         // 270336 floats
    unsigned short* Sb       = (unsigned short*)(ws + 270336); // 4*T*132 bf16 = 1081344 float-slots
    float*          chunkSum = ws + 1351680;               // 33792
    float*          chunkOff = ws + 1385472;               // 33792
    float*          TM       = ws + 1419264;               // 16384
                                                           // total ~5.74 MB

    mlp_scan_kernel<<<320, 256, 0, stream>>>(x1, x2, x3, x4, wq, bq, wk, bk,
                                             Q, Sb, chunkSum, TM);
    chunkscan_kernel<<<dim3(33, 4), 256, 0, stream>>>(chunkSum, chunkOff);
    out_kernel<<<1024, 256, 0, stream>>>(Q, Sb, chunkOff, TM, (float*)d_out);
}